// Round 4
// baseline (1190.475 us; speedup 1.0000x reference)
//
#include <hip/hip_runtime.h>

#define T_  30
#define B_  64
#define V_  32
#define F_  128
#define L_  64
#define LF_ 64
#define TH_ 20
#define H_  4
#define HD_ 32

// ---- bf16 helpers (some LDS intermediates bf16; all math fp32) ----
__device__ __forceinline__ float bf1(unsigned short u) {
    unsigned int x = ((unsigned int)u) << 16; float f; __builtin_memcpy(&f, &x, 4); return f;
}
__device__ __forceinline__ unsigned short f2bf(float f) {
    unsigned int x; __builtin_memcpy(&x, &f, 4);
    x += 0x7fffu + ((x >> 16) & 1u);          // round-to-nearest-even
    return (unsigned short)(x >> 16);
}

// dtype-agnostic 4-element load: idx4 indexes groups of 4 elements
__device__ __forceinline__ float4 ld4(const void* p, int idx4, bool isBf16) {
    if (isBf16) {
        ushort4 u = ((const ushort4*)p)[idx4];
        return make_float4(bf1(u.x), bf1(u.y), bf1(u.z), bf1(u.w));
    }
    return ((const float4*)p)[idx4];
}

// One block per (b,v). 256 threads = 4 waves. Inputs fp32 (probed), output FP32.
__global__ __launch_bounds__(256, 2)
void lane_attn_kernel(const void* __restrict__ veh,    // [T,B,V,F]
                      const void* __restrict__ lanes,  // [B,V,L,LF]
                      const void* __restrict__ maskp,  // [TH,B,V,L] uint8 or int32 (probed)
                      const void* __restrict__ Wk,     // [F,LF]
                      const void* __restrict__ Wv,     // [F,LF]
                      const void* __restrict__ Wq,     // [F,F]
                      const void* __restrict__ Wc,     // [F,F]
                      float* __restrict__ outp)        // [T,B,V,F] fp32
{
    const int bv  = blockIdx.x;
    const int tid = threadIdx.x;

    // sLanes (Phase A/B) and sAttn (Phase D/E) have disjoint lifetimes -> overlay.
    __shared__ __align__(16) unsigned short sLanesAttn[L_ * LF_];  // 8 KB  bf16
    __shared__ __align__(16) unsigned short sK[L_][F_ + 8];        // 17 KB bf16 (pad 16B)
    __shared__ __align__(16) unsigned short sV[L_][F_ + 8];        // 17 KB
    __shared__ __align__(16) float          sVeh[T_ * F_];         // 15 KB fp32 (exact residual)
    __shared__ __align__(16) float          sQ[T_ * F_];           // 15 KB fp32
    __shared__ __align__(16) float          sP[H_ * L_];           // 1 KB
    __shared__ int sOK[L_];
    __shared__ int sFlags[2];
    unsigned short* sLanes = sLanesAttn;          // [L_*LF_]
    unsigned short* sAttn  = sLanesAttn;          // [T_*F_] = 3840 <= 4096 ok
    // total ~75 KB -> 2 blocks/CU

    // ---------- Phase 0: dtype probes (wave 0; block-uniform via LDS) ----------
    if (tid < 64) {
        // Input probe: packed bf16 -> valid bf16 exponent ~64/64; fp32 mantissa ~8/64.
        const unsigned short* vh = (const unsigned short*)veh;
        const int field = (vh[2 * tid] >> 7) & 0xFF;
        const unsigned long long balD = __ballot(field >= 100 && field <= 130);
        // Mask probe: int32 little-endian {0,1} has byte 4e+1 == 0 always.
        const unsigned char* mb = (const unsigned char*)maskp;
        const unsigned long long balM = __ballot(mb[4 * tid + 1] != 0);
        if (tid == 0) {
            sFlags[0] = (__popcll(balD) >= 32);   // isBf16 inputs
            sFlags[1] = (balM != 0ULL);           // mask is byte-typed
        }
    }
    __syncthreads();
    const bool isBf16   = sFlags[0] != 0;
    const bool maskByte = sFlags[1] != 0;

    // ---------- Phase A: stage lanes (bf16) + vehicles (fp32), reduce mask ----------
    {
        const int base4 = bv * (L_ * LF_ / 4);
        for (int u = tid; u < (L_ * LF_) / 4; u += 256) {
            float4 x = ld4(lanes, base4 + u, isBf16);
            ushort4 y = { f2bf(x.x), f2bf(x.y), f2bf(x.z), f2bf(x.w) };
            *(ushort4*)&sLanes[u * 4] = y;
        }
    }
    {
        for (int u = tid; u < T_ * (F_ / 4); u += 256) {
            const int t = u >> 5, c = u & 31;
            const int row4 = (t * (B_ * V_) + bv) * (F_ / 4);
            float4 x = ld4(veh, row4 + c, isBf16);
            *(float4*)&sVeh[t * F_ + c * 4] = x;
        }
    }
    if (tid < L_) {
        const unsigned char* mb = (const unsigned char*)maskp;
        const int* mi = (const int*)maskp;
        int ok = 0;
        #pragma unroll
        for (int th = 0; th < TH_; ++th) {
            const size_t e = (size_t)th * (B_ * V_ * L_) + (size_t)bv * L_ + tid;
            ok |= maskByte ? (int)mb[e] : mi[e];
        }
        sOK[tid] = (ok != 0);
    }
    __syncthreads();

    // ---------- Phase B: K = lanes@Wk^T, V = lanes@Wv^T -> LDS bf16 ----------
    {
        const int f = tid & 127;
        const int lhalf = tid >> 7;
        float4 wk[16], wv[16];
        if (isBf16) {
            const ushort4* wkr = (const ushort4*)Wk + f * (LF_ / 4);
            const ushort4* wvr = (const ushort4*)Wv + f * (LF_ / 4);
            #pragma unroll
            for (int kc = 0; kc < 16; ++kc) {
                ushort4 a = wkr[kc], b = wvr[kc];
                wk[kc] = make_float4(bf1(a.x), bf1(a.y), bf1(a.z), bf1(a.w));
                wv[kc] = make_float4(bf1(b.x), bf1(b.y), bf1(b.z), bf1(b.w));
            }
        } else {
            const float4* wkr = (const float4*)Wk + f * (LF_ / 4);
            const float4* wvr = (const float4*)Wv + f * (LF_ / 4);
            #pragma unroll
            for (int kc = 0; kc < 16; ++kc) { wk[kc] = wkr[kc]; wv[kc] = wvr[kc]; }
        }
        #pragma unroll 2
        for (int li = 0; li < 32; ++li) {
            const int l = lhalf * 32 + li;
            float accK = 0.f, accV = 0.f;
            #pragma unroll
            for (int kc = 0; kc < 16; ++kc) {
                ushort4 lv = *(const ushort4*)&sLanes[l * LF_ + kc * 4];
                const float x0 = bf1(lv.x), x1 = bf1(lv.y), x2 = bf1(lv.z), x3 = bf1(lv.w);
                accK += x0*wk[kc].x + x1*wk[kc].y + x2*wk[kc].z + x3*wk[kc].w;
                accV += x0*wv[kc].x + x1*wv[kc].y + x2*wv[kc].z + x3*wv[kc].w;
            }
            sK[l][f] = f2bf(accK);
            sV[l][f] = f2bf(accV);
        }
    }
    __syncthreads();   // also ends sLanes lifetime

    // ---------- Phase C: Q[t,g] for all t (Wq read once per block) ----------
    {
        const int g = tid & 127;
        const int th2 = tid >> 7;
        float4 wq[32];
        if (isBf16) {
            const ushort4* wqr = (const ushort4*)Wq + g * (F_ / 4);
            #pragma unroll
            for (int kc = 0; kc < 32; ++kc) {
                ushort4 a = wqr[kc];
                wq[kc] = make_float4(bf1(a.x), bf1(a.y), bf1(a.z), bf1(a.w));
            }
        } else {
            const float4* wqr = (const float4*)Wq + g * (F_ / 4);
            #pragma unroll
            for (int kc = 0; kc < 32; ++kc) wq[kc] = wqr[kc];
        }
        float acc[15];
        #pragma unroll
        for (int j = 0; j < 15; ++j) acc[j] = 0.f;
        #pragma unroll 2
        for (int kc = 0; kc < 32; ++kc) {
            #pragma unroll
            for (int j = 0; j < 15; ++j) {
                float4 vv = *(const float4*)&sVeh[(th2 * 15 + j) * F_ + kc * 4];
                acc[j] += vv.x*wq[kc].x + vv.y*wq[kc].y + vv.z*wq[kc].z + vv.w*wq[kc].w;
            }
        }
        #pragma unroll
        for (int j = 0; j < 15; ++j)
            sQ[(th2 * 15 + j) * F_ + g] = acc[j] * 0.17677669529663687f;  // 1/sqrt(32)
    }
    __syncthreads();

    // ---------- Phase D: per-t scores -> masked softmax -> PV ----------
    for (int t = 0; t < T_; ++t) {
        {   // wave h owns head h; lane l owns attention-lane l
            const int h = tid >> 6, l = tid & 63;
            const float4* q4 = (const float4*)&sQ[t * F_ + h * HD_];
            float sc = 0.f;
            #pragma unroll
            for (int kc = 0; kc < HD_ / 4; ++kc) {
                ushort4 kv = *(const ushort4*)&sK[l][h * HD_ + kc * 4];
                float4 q = q4[kc];
                sc += bf1(kv.x)*q.x + bf1(kv.y)*q.y + bf1(kv.z)*q.z + bf1(kv.w)*q.w;
            }
            sc = sOK[l] ? sc : -1e9f;
            float m = sc;
            #pragma unroll
            for (int off = 32; off; off >>= 1) m = fmaxf(m, __shfl_xor(m, off));
            float p = __expf(sc - m);
            float s = p;
            #pragma unroll
            for (int off = 32; off; off >>= 1) s += __shfl_xor(s, off);
            sP[h * L_ + l] = p / s;
        }
        __syncthreads();
        if (tid < F_) {   // PV: thread owns feature f
            const int f = tid, h = tid >> 5;
            const float* prow = &sP[h * L_];
            float acc = 0.f;
            #pragma unroll
            for (int l = 0; l < L_; ++l) acc += prow[l] * bf1(sV[l][f]);
            sAttn[t * F_ + f] = f2bf(acc);
        }
        __syncthreads();
    }

    // ---------- Phase E: out = attn@Wc^T + veh -> FP32 ----------
    {
        const int g = tid & 127;
        const int th2 = tid >> 7;
        float4 wc[32];
        if (isBf16) {
            const ushort4* wcr = (const ushort4*)Wc + g * (F_ / 4);
            #pragma unroll
            for (int kc = 0; kc < 32; ++kc) {
                ushort4 a = wcr[kc];
                wc[kc] = make_float4(bf1(a.x), bf1(a.y), bf1(a.z), bf1(a.w));
            }
        } else {
            const float4* wcr = (const float4*)Wc + g * (F_ / 4);
            #pragma unroll
            for (int kc = 0; kc < 32; ++kc) wc[kc] = wcr[kc];
        }
        float acc[15];
        #pragma unroll
        for (int j = 0; j < 15; ++j) acc[j] = 0.f;
        #pragma unroll 2
        for (int kc = 0; kc < 32; ++kc) {
            #pragma unroll
            for (int j = 0; j < 15; ++j) {
                ushort4 av = *(const ushort4*)&sAttn[(th2 * 15 + j) * F_ + kc * 4];
                acc[j] += bf1(av.x)*wc[kc].x + bf1(av.y)*wc[kc].y
                        + bf1(av.z)*wc[kc].z + bf1(av.w)*wc[kc].w;
            }
        }
        #pragma unroll
        for (int j = 0; j < 15; ++j) {
            const int t = th2 * 15 + j;
            outp[((size_t)t * (B_ * V_) + bv) * F_ + g] = acc[j] + sVeh[t * F_ + g];
        }
    }
}

extern "C" void kernel_launch(void* const* d_in, const int* in_sizes, int n_in,
                              void* d_out, int out_size, void* d_ws, size_t ws_size,
                              hipStream_t stream) {
    (void)in_sizes; (void)n_in; (void)d_ws; (void)ws_size; (void)out_size;
    lane_attn_kernel<<<dim3(B_ * V_), dim3(256), 0, stream>>>(
        d_in[0], d_in[1], d_in[2], d_in[3], d_in[4], d_in[5], d_in[6],
        (float*)d_out);
}

// Round 5
// 529.667 us; speedup vs baseline: 2.2476x; 2.2476x over previous
//
#include <hip/hip_runtime.h>

#define T_  30
#define B_  64
#define V_  32
#define F_  128
#define L_  64
#define LF_ 64
#define TH_ 20
#define H_  4
#define HD_ 32

// ---- bf16 helpers (some LDS intermediates bf16; all math fp32) ----
__device__ __forceinline__ float bf1(unsigned short u) {
    unsigned int x = ((unsigned int)u) << 16; float f; __builtin_memcpy(&f, &x, 4); return f;
}
__device__ __forceinline__ unsigned short f2bf(float f) {
    unsigned int x; __builtin_memcpy(&x, &f, 4);
    x += 0x7fffu + ((x >> 16) & 1u);          // round-to-nearest-even
    return (unsigned short)(x >> 16);
}

// dtype-agnostic 4-element load: idx4 indexes groups of 4 elements
__device__ __forceinline__ float4 ld4(const void* p, int idx4, bool isBf16) {
    if (isBf16) {
        ushort4 u = ((const ushort4*)p)[idx4];
        return make_float4(bf1(u.x), bf1(u.y), bf1(u.z), bf1(u.w));
    }
    return ((const float4*)p)[idx4];
}

// One block per (b,v). 256 threads = 4 waves. Inputs fp32 (probed), output FP32.
__global__ __launch_bounds__(256, 2)
void lane_attn_kernel(const void* __restrict__ veh,    // [T,B,V,F]
                      const void* __restrict__ lanes,  // [B,V,L,LF]
                      const void* __restrict__ maskp,  // [TH,B,V,L] uint8 or int32 (probed)
                      const void* __restrict__ Wk,     // [F,LF]
                      const void* __restrict__ Wv,     // [F,LF]
                      const void* __restrict__ Wq,     // [F,F]
                      const void* __restrict__ Wc,     // [F,F]
                      float* __restrict__ outp)        // [T,B,V,F] fp32
{
    const int bv  = blockIdx.x;
    const int tid = threadIdx.x;

    // sLanes (Phase A/B) and sAttn (Phase D/E) have disjoint lifetimes -> overlay.
    __shared__ __align__(16) unsigned short sLanesAttn[L_ * LF_];  // 8 KB  bf16
    __shared__ __align__(16) unsigned short sK[L_][F_ + 8];        // 17 KB bf16
    __shared__ __align__(16) unsigned short sV[L_][F_ + 8];        // 17 KB
    __shared__ __align__(16) float          sVeh[T_ * F_];         // 15 KB fp32 (exact residual)
    __shared__ __align__(16) float          sQ[T_ * F_];           // 15 KB fp32
    __shared__ __align__(16) float          sP[H_ * L_];           // 1 KB
    __shared__ int sOK[L_];
    __shared__ int sFlags[2];
    unsigned short* sLanes = sLanesAttn;          // [L_*LF_]
    unsigned short* sAttn  = sLanesAttn;          // [T_*F_] = 3840 <= 4096 ok

    // ---------- Phase 0: dtype probes (wave 0; block-uniform via LDS) ----------
    if (tid < 64) {
        const unsigned short* vh = (const unsigned short*)veh;
        const int field = (vh[2 * tid] >> 7) & 0xFF;
        const unsigned long long balD = __ballot(field >= 100 && field <= 130);
        const unsigned char* mb = (const unsigned char*)maskp;
        const unsigned long long balM = __ballot(mb[4 * tid + 1] != 0);
        if (tid == 0) {
            sFlags[0] = (__popcll(balD) >= 32);   // isBf16 inputs
            sFlags[1] = (balM != 0ULL);           // mask is byte-typed
        }
    }
    __syncthreads();
    const bool isBf16   = sFlags[0] != 0;
    const bool maskByte = sFlags[1] != 0;

    // ---------- Phase A: stage lanes (bf16) + vehicles (fp32), reduce mask ----------
    {
        const int base4 = bv * (L_ * LF_ / 4);
        for (int u = tid; u < (L_ * LF_) / 4; u += 256) {
            float4 x = ld4(lanes, base4 + u, isBf16);
            ushort4 y = { f2bf(x.x), f2bf(x.y), f2bf(x.z), f2bf(x.w) };
            *(ushort4*)&sLanes[u * 4] = y;
        }
        for (int u = tid; u < T_ * (F_ / 4); u += 256) {
            const int t = u >> 5, c = u & 31;
            const int row4 = (t * (B_ * V_) + bv) * (F_ / 4);
            float4 x = ld4(veh, row4 + c, isBf16);
            *(float4*)&sVeh[t * F_ + c * 4] = x;
        }
    }
    if (tid < L_) {
        const unsigned char* mb = (const unsigned char*)maskp;
        const int* mi = (const int*)maskp;
        int ok = 0;
        #pragma unroll
        for (int th = 0; th < TH_; ++th) {
            const size_t e = (size_t)th * (B_ * V_ * L_) + (size_t)bv * L_ + tid;
            ok |= maskByte ? (int)mb[e] : mi[e];
        }
        sOK[tid] = (ok != 0);
    }
    __syncthreads();

    // ---------- Phase B: K = lanes@Wk^T, V = lanes@Wv^T -> LDS bf16 ----------
    // thread = (f, matrix). Holds ONE weight row (16 float4 = 64 VGPR). Lane reads
    // from sLanes are wave-uniform (address independent of f) -> LDS broadcast.
    {
        const int f   = tid & 127;
        const int mat = tid >> 7;                 // 0 -> K, 1 -> V (wave-uniform)
        const void* W = mat ? Wv : Wk;
        float4 w[16];
        if (isBf16) {
            const ushort4* wr = (const ushort4*)W + f * (LF_ / 4);
            #pragma unroll
            for (int kc = 0; kc < 16; ++kc) {
                ushort4 a = wr[kc];
                w[kc] = make_float4(bf1(a.x), bf1(a.y), bf1(a.z), bf1(a.w));
            }
        } else {
            const float4* wr = (const float4*)W + f * (LF_ / 4);
            #pragma unroll
            for (int kc = 0; kc < 16; ++kc) w[kc] = wr[kc];
        }
        unsigned short* dst = mat ? &sV[0][0] : &sK[0][0];
        for (int l = 0; l < L_; ++l) {
            float accA = 0.f, accB = 0.f;         // two chains for FMA-latency ILP
            #pragma unroll
            for (int kc = 0; kc < 16; kc += 2) {
                ushort4 x0 = *(const ushort4*)&sLanes[l * LF_ + kc * 4];
                ushort4 x1 = *(const ushort4*)&sLanes[l * LF_ + kc * 4 + 4];
                accA += bf1(x0.x)*w[kc].x + bf1(x0.y)*w[kc].y
                      + bf1(x0.z)*w[kc].z + bf1(x0.w)*w[kc].w;
                accB += bf1(x1.x)*w[kc+1].x + bf1(x1.y)*w[kc+1].y
                      + bf1(x1.z)*w[kc+1].z + bf1(x1.w)*w[kc+1].w;
            }
            dst[l * (F_ + 8) + f] = f2bf(accA + accB);
        }
    }
    __syncthreads();   // also ends sLanes lifetime

    // ---------- Phase C: Q[t,g] for all t. In-loop weight loads (1 float4 live). ----------
    {
        const int g   = tid & 127;
        const int th2 = tid >> 7;                 // t-half
        float acc[15];
        #pragma unroll
        for (int j = 0; j < 15; ++j) acc[j] = 0.f;
        for (int kc = 0; kc < 32; ++kc) {
            float4 wq = ld4(Wq, g * (F_ / 4) + kc, isBf16);
            #pragma unroll
            for (int j = 0; j < 15; ++j) {
                float4 vv = *(const float4*)&sVeh[(th2 * 15 + j) * F_ + kc * 4];
                acc[j] += vv.x*wq.x + vv.y*wq.y + vv.z*wq.z + vv.w*wq.w;
            }
        }
        #pragma unroll
        for (int j = 0; j < 15; ++j)
            sQ[(th2 * 15 + j) * F_ + g] = acc[j] * 0.17677669529663687f;  // 1/sqrt(32)
    }
    __syncthreads();

    // ---------- Phase D: per-t scores -> masked softmax -> PV ----------
    for (int t = 0; t < T_; ++t) {
        {   // wave h owns head h; lane l owns attention-lane l
            const int h = tid >> 6, l = tid & 63;
            const float4* q4 = (const float4*)&sQ[t * F_ + h * HD_];
            float sc = 0.f;
            #pragma unroll
            for (int kc = 0; kc < HD_ / 4; ++kc) {
                ushort4 kv = *(const ushort4*)&sK[l][h * HD_ + kc * 4];
                float4 q = q4[kc];
                sc += bf1(kv.x)*q.x + bf1(kv.y)*q.y + bf1(kv.z)*q.z + bf1(kv.w)*q.w;
            }
            sc = sOK[l] ? sc : -1e9f;
            float m = sc;
            #pragma unroll
            for (int off = 32; off; off >>= 1) m = fmaxf(m, __shfl_xor(m, off));
            float p = __expf(sc - m);
            float s = p;
            #pragma unroll
            for (int off = 32; off; off >>= 1) s += __shfl_xor(s, off);
            sP[h * L_ + l] = p / s;
        }
        __syncthreads();
        if (tid < F_) {   // PV: thread owns feature f
            const int f = tid, h = tid >> 5;
            const float* prow = &sP[h * L_];
            float accA = 0.f, accB = 0.f;
            #pragma unroll
            for (int l = 0; l < L_; l += 2) {
                accA += prow[l]     * bf1(sV[l][f]);
                accB += prow[l + 1] * bf1(sV[l + 1][f]);
            }
            sAttn[t * F_ + f] = f2bf(accA + accB);
        }
        __syncthreads();
    }

    // ---------- Phase E: out = attn@Wc^T + veh -> FP32. In-loop weight loads. ----------
    {
        const int g   = tid & 127;
        const int th2 = tid >> 7;
        float acc[15];
        #pragma unroll
        for (int j = 0; j < 15; ++j) acc[j] = 0.f;
        for (int kc = 0; kc < 32; ++kc) {
            float4 wc = ld4(Wc, g * (F_ / 4) + kc, isBf16);
            #pragma unroll
            for (int j = 0; j < 15; ++j) {
                ushort4 av = *(const ushort4*)&sAttn[(th2 * 15 + j) * F_ + kc * 4];
                acc[j] += bf1(av.x)*wc.x + bf1(av.y)*wc.y
                        + bf1(av.z)*wc.z + bf1(av.w)*wc.w;
            }
        }
        #pragma unroll
        for (int j = 0; j < 15; ++j) {
            const int t = th2 * 15 + j;
            outp[((size_t)t * (B_ * V_) + bv) * F_ + g] = acc[j] + sVeh[t * F_ + g];
        }
    }
}

extern "C" void kernel_launch(void* const* d_in, const int* in_sizes, int n_in,
                              void* d_out, int out_size, void* d_ws, size_t ws_size,
                              hipStream_t stream) {
    (void)in_sizes; (void)n_in; (void)d_ws; (void)ws_size; (void)out_size;
    lane_attn_kernel<<<dim3(B_ * V_), dim3(256), 0, stream>>>(
        d_in[0], d_in[1], d_in[2], d_in[3], d_in[4], d_in[5], d_in[6],
        (float*)d_out);
}

// Round 6
// 231.339 us; speedup vs baseline: 5.1460x; 2.2896x over previous
//
#include <hip/hip_runtime.h>

#define T_  30
#define B_  64
#define V_  32
#define F_  128
#define L_  64
#define LF_ 64
#define TH_ 20
#define H_  4
#define HD_ 32

typedef __attribute__((ext_vector_type(8))) short bf16x8;   // 8 bf16 = 4 VGPR
typedef __attribute__((ext_vector_type(4))) float f32x4;
#define MFMA(a,b,c) __builtin_amdgcn_mfma_f32_16x16x32_bf16(a, b, c, 0, 0, 0)

__device__ __forceinline__ float bf1(unsigned short u) {
    unsigned int x = ((unsigned int)u) << 16; float f; __builtin_memcpy(&f, &x, 4); return f;
}
__device__ __forceinline__ unsigned short f2bf(float f) {
    unsigned int x; __builtin_memcpy(&x, &f, 4);
    x += 0x7fffu + ((x >> 16) & 1u);          // round-to-nearest-even
    return (unsigned short)(x >> 16);
}
__device__ __forceinline__ float4 ld4(const void* p, int idx4, bool isBf16) {
    if (isBf16) {
        ushort4 u = ((const ushort4*)p)[idx4];
        return make_float4(bf1(u.x), bf1(u.y), bf1(u.z), bf1(u.w));
    }
    return ((const float4*)p)[idx4];
}
__device__ __forceinline__ void st4bf(unsigned short* p, f32x4 v) {
    ushort4 u = { f2bf(v[0]), f2bf(v[1]), f2bf(v[2]), f2bf(v[3]) };
    *(ushort4*)p = u;   // 8B LDS write
}

// ---------------- weight fp32->bf16 conversion into d_ws ----------------
// ws layout (ushort elems): Wk @0 [128*64], Wv @8192, Wq @16384 [128*128], Wc @32768
__global__ __launch_bounds__(256)
void cvt_weights(const void* __restrict__ Wk, const void* __restrict__ Wv,
                 const void* __restrict__ Wq, const void* __restrict__ Wc,
                 unsigned short* __restrict__ wsW)
{
    __shared__ int flag;
    const int tid = threadIdx.x;
    if (tid < 64) {   // dtype probe on Wk (σ=0.125 -> bf16 exponents in [100,130])
        const unsigned short* p = (const unsigned short*)Wk;
        const int fld = (p[2 * tid] >> 7) & 0xFF;
        const unsigned long long bal = __ballot(fld >= 100 && fld <= 130);
        if (tid == 0) flag = (__popcll(bal) >= 32);
    }
    __syncthreads();
    const bool isBf16 = flag != 0;
    const int idx = blockIdx.x * 256 + tid;
    if (idx >= 49152) return;
    const void* src; int rel, base;
    if      (idx < 8192)  { src = Wk; rel = idx;         base = 0;     }
    else if (idx < 16384) { src = Wv; rel = idx - 8192;  base = 8192;  }
    else if (idx < 32768) { src = Wq; rel = idx - 16384; base = 16384; }
    else                  { src = Wc; rel = idx - 32768; base = 32768; }
    const float v = isBf16 ? bf1(((const unsigned short*)src)[rel])
                           : ((const float*)src)[rel];
    wsW[base + rel] = f2bf(v);
}

// ---------------- main fused kernel: one block per (b,v), 4 waves ----------------
__global__ __launch_bounds__(256, 2)
void lane_attn_kernel(const void* __restrict__ veh,    // [T,B,V,F]
                      const void* __restrict__ lanes,  // [B,V,L,LF]
                      const void* __restrict__ maskp,  // [TH,B,V,L] uint8 or int32 (probed)
                      const unsigned short* __restrict__ wsW,  // bf16 weights
                      float* __restrict__ outp)        // [T,B,V,F] fp32
{
    const int bv   = blockIdx.x;
    const int tid  = threadIdx.x;
    const int w    = tid >> 6;     // wave 0..3
    const int lane = tid & 63;
    const int quad = lane >> 4;    // 0..3
    const int lm   = lane & 15;

    const unsigned short* wsWk = wsW;
    const unsigned short* wsWv = wsW + 8192;
    const unsigned short* wsWq = wsW + 16384;
    const unsigned short* wsWc = wsW + 32768;

    // LDS (all bf16 unless noted). sLanes+sVeh overlay sS (disjoint lifetimes).
    __shared__ __align__(16) unsigned short sRegion[9472]; // max(5120+4352, 9216)
    __shared__ __align__(16) unsigned short sK [64 * 136]; // K[l][f], stride 136
    __shared__ __align__(16) unsigned short sVt[128 * 72]; // V^T[f][l], stride 72
    __shared__ __align__(16) unsigned short sQ [32 * 136]; // Q[t][g] (pre-scaled)
    __shared__ __align__(16) unsigned short sO [32 * 136]; // attn out [t][f]
    __shared__ int sOK[L_];
    __shared__ int sFlags[2];
    unsigned short* sLanes = sRegion;          // [64][80]
    unsigned short* sVehB  = sRegion + 5120;   // [32][136] bf16 (rows 30,31 zero)
    unsigned short* sS     = sRegion;          // [4][32][72] scores -> P (after barrier)

    // ---------- probes (wave-0; block-uniform) ----------
    if (tid < 64) {
        const unsigned short* vh = (const unsigned short*)veh;
        const int field = (vh[2 * tid] >> 7) & 0xFF;
        const unsigned long long balD = __ballot(field >= 100 && field <= 130);
        const unsigned char* mb = (const unsigned char*)maskp;
        const unsigned long long balM = __ballot(mb[4 * tid + 1] != 0);
        if (tid == 0) {
            sFlags[0] = (__popcll(balD) >= 32);   // inputs are bf16
            sFlags[1] = (balM != 0ULL);           // mask is byte-typed
        }
    }
    __syncthreads();
    const bool isBf16   = sFlags[0] != 0;
    const bool maskByte = sFlags[1] != 0;

    // ---------- Phase A: stage lanes[64][80] + veh[32][136] (bf16), mask-OR ----------
    for (int u = tid; u < 64 * 16; u += 256) {          // lanes: 64 rows x 16 float4
        const int l = u >> 4, c4 = u & 15;
        float4 x = ld4(lanes, bv * (L_ * LF_ / 4) + u, isBf16);
        ushort4 y = { f2bf(x.x), f2bf(x.y), f2bf(x.z), f2bf(x.w) };
        *(ushort4*)&sLanes[l * 80 + c4 * 4] = y;
    }
    for (int u = tid; u < 32 * 32; u += 256) {          // veh: 32 rows x 32 float4
        const int t = u >> 5, c4 = u & 31;
        ushort4 y = {0, 0, 0, 0};
        if (t < T_) {
            float4 x = ld4(veh, (t * (B_ * V_) + bv) * (F_ / 4) + c4, isBf16);
            y.x = f2bf(x.x); y.y = f2bf(x.y); y.z = f2bf(x.z); y.w = f2bf(x.w);
        }
        *(ushort4*)&sVehB[t * 136 + c4 * 4] = y;
    }
    if (tid < L_) {
        const unsigned char* mb = (const unsigned char*)maskp;
        const int* mi = (const int*)maskp;
        int ok = 0;
        #pragma unroll
        for (int th = 0; th < TH_; ++th) {
            const size_t e = (size_t)th * (B_ * V_ * L_) + (size_t)bv * L_ + tid;
            ok |= maskByte ? (int)mb[e] : mi[e];
        }
        sOK[tid] = (ok != 0);
    }
    __syncthreads();

    // ---------- Phase B: K/V projection (MFMA). wave w -> f-tiles {2w,2w+1} ----------
    {
        const int fbase = w * 32;
        f32x4 accK[2][4], accV[2][4];
        #pragma unroll
        for (int nt = 0; nt < 2; ++nt)
            #pragma unroll
            for (int mt = 0; mt < 4; ++mt) { accK[nt][mt] = (f32x4)0.f; accV[nt][mt] = (f32x4)0.f; }
        #pragma unroll
        for (int kt = 0; kt < 2; ++kt) {
            bf16x8 a[4];
            #pragma unroll
            for (int mt = 0; mt < 4; ++mt)
                a[mt] = *(const bf16x8*)&sLanes[(mt * 16 + lm) * 80 + kt * 32 + quad * 8];
            #pragma unroll
            for (int nt = 0; nt < 2; ++nt) {
                const int f = fbase + nt * 16 + lm;
                bf16x8 bk = *(const bf16x8*)&wsWk[f * 64 + kt * 32 + quad * 8];
                bf16x8 bb = *(const bf16x8*)&wsWv[f * 64 + kt * 32 + quad * 8];
                #pragma unroll
                for (int mt = 0; mt < 4; ++mt) {
                    accK[nt][mt] = MFMA(a[mt], bk, accK[nt][mt]);
                    accV[nt][mt] = MFMA(a[mt], bb, accV[nt][mt]);
                }
            }
        }
        #pragma unroll
        for (int nt = 0; nt < 2; ++nt) {
            const int f = fbase + nt * 16 + lm;
            #pragma unroll
            for (int mt = 0; mt < 4; ++mt) {
                const int l0 = mt * 16 + quad * 4;
                #pragma unroll
                for (int r = 0; r < 4; ++r) sK[(l0 + r) * 136 + f] = f2bf(accK[nt][mt][r]);
                st4bf(&sVt[f * 72 + l0], accV[nt][mt]);   // V^T: consecutive l -> b64
            }
        }
    }

    // ---------- Phase C: Q projection (MFMA), pre-scaled 1/sqrt(hd) ----------
    {
        const int gbase = w * 32;
        f32x4 acc[2][2];
        #pragma unroll
        for (int nt = 0; nt < 2; ++nt)
            #pragma unroll
            for (int mt = 0; mt < 2; ++mt) acc[nt][mt] = (f32x4)0.f;
        #pragma unroll
        for (int kt = 0; kt < 4; ++kt) {
            bf16x8 a[2];
            #pragma unroll
            for (int mt = 0; mt < 2; ++mt)
                a[mt] = *(const bf16x8*)&sVehB[(mt * 16 + lm) * 136 + kt * 32 + quad * 8];
            #pragma unroll
            for (int nt = 0; nt < 2; ++nt) {
                const int g = gbase + nt * 16 + lm;
                bf16x8 b = *(const bf16x8*)&wsWq[g * 128 + kt * 32 + quad * 8];
                #pragma unroll
                for (int mt = 0; mt < 2; ++mt) acc[nt][mt] = MFMA(a[mt], b, acc[nt][mt]);
            }
        }
        const float sc = 0.17677669529663687f;   // 1/sqrt(32)
        #pragma unroll
        for (int nt = 0; nt < 2; ++nt) {
            const int g = gbase + nt * 16 + lm;
            #pragma unroll
            for (int mt = 0; mt < 2; ++mt) {
                const int t0 = mt * 16 + quad * 4;
                #pragma unroll
                for (int r = 0; r < 4; ++r) sQ[(t0 + r) * 136 + g] = f2bf(acc[nt][mt][r] * sc);
            }
        }
    }
    __syncthreads();   // ends sLanes/sVehB lifetime; sS region live from here

    // ---------- Scores: S^T[l][t] = K[l][:h] . Q[t][:h]  (wave = head) ----------
    {
        const int h = w;
        bf16x8 a[4], b[2];
        #pragma unroll
        for (int mt = 0; mt < 4; ++mt)
            a[mt] = *(const bf16x8*)&sK[(mt * 16 + lm) * 136 + h * 32 + quad * 8];
        #pragma unroll
        for (int nt = 0; nt < 2; ++nt)
            b[nt] = *(const bf16x8*)&sQ[(nt * 16 + lm) * 136 + h * 32 + quad * 8];
        #pragma unroll
        for (int mt = 0; mt < 4; ++mt) {
            #pragma unroll
            for (int nt = 0; nt < 2; ++nt) {
                f32x4 acc = MFMA(a[mt], b[nt], (f32x4)0.f);
                const int t = nt * 16 + lm;          // D col
                st4bf(&sS[(h * 32 + t) * 72 + mt * 16 + quad * 4], acc);  // rows l..l+3
            }
        }
    }
    __syncthreads();

    // ---------- Softmax over l per (h,t); P written in place (bf16) ----------
    {
        const int h = w, l = lane;
        const bool ok = sOK[l] != 0;
        for (int t = 0; t < T_; ++t) {
            float v = bf1(sS[(h * 32 + t) * 72 + l]);
            v = ok ? v : -1e9f;
            float m = v;
            #pragma unroll
            for (int off = 32; off; off >>= 1) m = fmaxf(m, __shfl_xor(m, off));
            float p = __expf(v - m);
            float s = p;
            #pragma unroll
            for (int off = 32; off; off >>= 1) s += __shfl_xor(s, off);
            sS[(h * 32 + t) * 72 + l] = f2bf(p / s);
        }
        sS[(h * 32 + 30) * 72 + l] = 0;   // pad rows must be finite for PV A-frags
        sS[(h * 32 + 31) * 72 + l] = 0;
    }
    __syncthreads();

    // ---------- PV: O[t][d] = sum_l P[t][l] V[l][d]  (wave = head) ----------
    {
        const int h = w;
        f32x4 acc[2][2];
        #pragma unroll
        for (int mt = 0; mt < 2; ++mt)
            #pragma unroll
            for (int nt = 0; nt < 2; ++nt) acc[mt][nt] = (f32x4)0.f;
        #pragma unroll
        for (int kt = 0; kt < 2; ++kt) {
            bf16x8 a[2], b[2];
            #pragma unroll
            for (int mt = 0; mt < 2; ++mt)
                a[mt] = *(const bf16x8*)&sS[(h * 32 + mt * 16 + lm) * 72 + kt * 32 + quad * 8];
            #pragma unroll
            for (int nt = 0; nt < 2; ++nt)
                b[nt] = *(const bf16x8*)&sVt[(h * 32 + nt * 16 + lm) * 72 + kt * 32 + quad * 8];
            #pragma unroll
            for (int mt = 0; mt < 2; ++mt)
                #pragma unroll
                for (int nt = 0; nt < 2; ++nt) acc[mt][nt] = MFMA(a[mt], b[nt], acc[mt][nt]);
        }
        #pragma unroll
        for (int mt = 0; mt < 2; ++mt) {
            #pragma unroll
            for (int nt = 0; nt < 2; ++nt) {
                const int f  = h * 32 + nt * 16 + lm;   // D col
                const int t0 = mt * 16 + quad * 4;      // D rows
                #pragma unroll
                for (int r = 0; r < 4; ++r) sO[(t0 + r) * 136 + f] = f2bf(acc[mt][nt][r]);
            }
        }
    }
    __syncthreads();

    // ---------- Phase E: out = O @ Wc^T + veh (fp32 store) ----------
    {
        const int gbase = w * 32;
        f32x4 acc[2][2];
        #pragma unroll
        for (int nt = 0; nt < 2; ++nt)
            #pragma unroll
            for (int mt = 0; mt < 2; ++mt) acc[nt][mt] = (f32x4)0.f;
        #pragma unroll
        for (int kt = 0; kt < 4; ++kt) {
            bf16x8 a[2];
            #pragma unroll
            for (int mt = 0; mt < 2; ++mt)
                a[mt] = *(const bf16x8*)&sO[(mt * 16 + lm) * 136 + kt * 32 + quad * 8];
            #pragma unroll
            for (int nt = 0; nt < 2; ++nt) {
                const int g = gbase + nt * 16 + lm;
                bf16x8 b = *(const bf16x8*)&wsWc[g * 128 + kt * 32 + quad * 8];
                #pragma unroll
                for (int mt = 0; mt < 2; ++mt) acc[nt][mt] = MFMA(a[mt], b, acc[nt][mt]);
            }
        }
        #pragma unroll
        for (int nt = 0; nt < 2; ++nt) {
            const int g = gbase + nt * 16 + lm;
            #pragma unroll
            for (int mt = 0; mt < 2; ++mt) {
                const int t0 = mt * 16 + quad * 4;
                #pragma unroll
                for (int r = 0; r < 4; ++r) {
                    const int t = t0 + r;
                    if (t < T_) {
                        const size_t off = ((size_t)t * (B_ * V_) + bv) * F_ + g;
                        const float res = isBf16 ? bf1(((const unsigned short*)veh)[off])
                                                 : ((const float*)veh)[off];
                        outp[off] = acc[nt][mt][r] + res;
                    }
                }
            }
        }
    }
}

extern "C" void kernel_launch(void* const* d_in, const int* in_sizes, int n_in,
                              void* d_out, int out_size, void* d_ws, size_t ws_size,
                              hipStream_t stream) {
    (void)in_sizes; (void)n_in; (void)out_size; (void)ws_size;
    unsigned short* wsW = (unsigned short*)d_ws;   // 98304 B used
    cvt_weights<<<dim3(192), dim3(256), 0, stream>>>(d_in[3], d_in[4], d_in[5], d_in[6], wsW);
    lane_attn_kernel<<<dim3(B_ * V_), dim3(256), 0, stream>>>(
        d_in[0], d_in[1], d_in[2], wsW, (float*)d_out);
}

// Round 7
// 186.307 us; speedup vs baseline: 6.3899x; 1.2417x over previous
//
#include <hip/hip_runtime.h>

#define T_  30
#define B_  64
#define V_  32
#define F_  128
#define L_  64
#define LF_ 64
#define TH_ 20
#define H_  4
#define HD_ 32

typedef __attribute__((ext_vector_type(8))) short bf16x8;   // 8 bf16 = 4 VGPR
typedef __attribute__((ext_vector_type(4))) float f32x4;
#define MFMA(a,b,c) __builtin_amdgcn_mfma_f32_16x16x32_bf16(a, b, c, 0, 0, 0)

__device__ __forceinline__ float bf1(unsigned short u) {
    unsigned int x = ((unsigned int)u) << 16; float f; __builtin_memcpy(&f, &x, 4); return f;
}
__device__ __forceinline__ unsigned short f2bf(float f) {
    unsigned int x; __builtin_memcpy(&x, &f, 4);
    x += 0x7fffu + ((x >> 16) & 1u);          // round-to-nearest-even
    return (unsigned short)(x >> 16);
}
__device__ __forceinline__ float4 ld4(const void* p, int idx4, bool isBf16) {
    if (isBf16) {
        ushort4 u = ((const ushort4*)p)[idx4];
        return make_float4(bf1(u.x), bf1(u.y), bf1(u.z), bf1(u.w));
    }
    return ((const float4*)p)[idx4];
}
__device__ __forceinline__ void st4bf(unsigned short* p, f32x4 v) {
    ushort4 u = { f2bf(v[0]), f2bf(v[1]), f2bf(v[2]), f2bf(v[3]) };
    *(ushort4*)p = u;
}
// Load one MFMA B-fragment (8 bf16) from a weight matrix of either dtype.
// off is an element offset, multiple of 8.
__device__ __forceinline__ bf16x8 ldWfrag(const void* W, int off, bool isBf16) {
    if (isBf16) return *(const bf16x8*)((const unsigned short*)W + off);
    const float* p = (const float*)W + off;
    float4 a = *(const float4*)p;
    float4 b = *(const float4*)(p + 4);
    bf16x8 r;
    r[0] = (short)f2bf(a.x); r[1] = (short)f2bf(a.y);
    r[2] = (short)f2bf(a.z); r[3] = (short)f2bf(a.w);
    r[4] = (short)f2bf(b.x); r[5] = (short)f2bf(b.y);
    r[6] = (short)f2bf(b.z); r[7] = (short)f2bf(b.w);
    return r;
}

// One block per (b,v). 4 waves; wave w owns head w and f/g-slice [32w,32w+32).
// Only 3 barriers: all other phase transitions are wave-local in LDS.
__global__ __launch_bounds__(256, 2)
void lane_attn_kernel(const void* __restrict__ veh,    // [T,B,V,F]
                      const void* __restrict__ lanes,  // [B,V,L,LF]
                      const void* __restrict__ maskp,  // [TH,B,V,L] uint8 or int32 (probed)
                      const void* __restrict__ Wk, const void* __restrict__ Wv,
                      const void* __restrict__ Wq, const void* __restrict__ Wc,
                      float* __restrict__ outp)        // [T,B,V,F] fp32
{
    const int bv   = blockIdx.x;
    const int tid  = threadIdx.x;
    const int w    = tid >> 6;     // wave / head
    const int lane = tid & 63;
    const int quad = lane >> 4;
    const int lm   = lane & 15;
    const int fbase = w * 32;

    // LDS overlays (ushort units):
    //   sQ    @0     [32][136]  (written C, read scores — wave-col-local)
    //   sO    @0     [32][136]  (written PV cols 32w.., disjoint from sQ cols of other waves)
    //   sLanes@4352  [64][80]   (A..B)
    //   sVehB @9472  [32][136]  (A..C)
    //   sS    @4352  [4][32][72](scores..PV, overlays sLanes+sVehB after barrier 2)
    __shared__ __align__(16) unsigned short sRegion[13824];
    __shared__ __align__(16) unsigned short sK [64 * 136];
    __shared__ __align__(16) unsigned short sVt[128 * 72];
    unsigned short* sQ     = sRegion;
    unsigned short* sO     = sRegion;
    unsigned short* sLanes = sRegion + 4352;
    unsigned short* sVehB  = sRegion + 9472;
    unsigned short* sS     = sRegion + 4352;

    // ---------- per-wave probes (wave-uniform, no LDS/barrier) ----------
    const unsigned short* vh16 = (const unsigned short*)veh;
    const int field = (vh16[2 * lane] >> 7) & 0xFF;
    const bool isBf16 = __popcll(__ballot(field >= 100 && field <= 130)) >= 32;
    const unsigned char* mbp = (const unsigned char*)maskp;
    const bool maskByte = (__ballot(mbp[4 * lane + 1] != 0) != 0ULL);

    // ---------- per-lane mask OR over TH (l = lane), kept in a register ----------
    bool ok;
    {
        const int* mi = (const int*)maskp;
        int o = 0;
        #pragma unroll
        for (int th = 0; th < TH_; ++th) {
            const size_t e = (size_t)th * (B_ * V_ * L_) + (size_t)bv * L_ + lane;
            o |= maskByte ? (int)mbp[e] : mi[e];
        }
        ok = (o != 0);
    }

    // ---------- preload weight fragments for B and C (registers, hides L2 latency) ----------
    bf16x8 wbK[2][2], wbV[2][2], wq[4][2];
    #pragma unroll
    for (int kt = 0; kt < 2; ++kt)
        #pragma unroll
        for (int nt = 0; nt < 2; ++nt) {
            const int off = (fbase + nt * 16 + lm) * 64 + kt * 32 + quad * 8;
            wbK[kt][nt] = ldWfrag(Wk, off, isBf16);
            wbV[kt][nt] = ldWfrag(Wv, off, isBf16);
        }
    #pragma unroll
    for (int kt = 0; kt < 4; ++kt)
        #pragma unroll
        for (int nt = 0; nt < 2; ++nt)
            wq[kt][nt] = ldWfrag(Wq, (fbase + nt * 16 + lm) * 128 + kt * 32 + quad * 8, isBf16);

    // ---------- Phase A: stage lanes[64][80] + veh[32][136] as bf16 ----------
    for (int u = tid; u < 64 * 16; u += 256) {
        const int l = u >> 4, c4 = u & 15;
        float4 x = ld4(lanes, bv * (L_ * LF_ / 4) + u, isBf16);
        ushort4 y = { f2bf(x.x), f2bf(x.y), f2bf(x.z), f2bf(x.w) };
        *(ushort4*)&sLanes[l * 80 + c4 * 4] = y;
    }
    for (int u = tid; u < 32 * 32; u += 256) {
        const int t = u >> 5, c4 = u & 31;
        ushort4 y = {0, 0, 0, 0};
        if (t < T_) {
            float4 x = ld4(veh, (t * (B_ * V_) + bv) * (F_ / 4) + c4, isBf16);
            y.x = f2bf(x.x); y.y = f2bf(x.y); y.z = f2bf(x.z); y.w = f2bf(x.w);
        }
        *(ushort4*)&sVehB[t * 136 + c4 * 4] = y;
    }
    __syncthreads();   // barrier 1: staging visible to all waves

    // ---------- Phase B: K/V projection (wave-local f-slice) ----------
    {
        f32x4 accK[2][4], accV[2][4];
        #pragma unroll
        for (int nt = 0; nt < 2; ++nt)
            #pragma unroll
            for (int mt = 0; mt < 4; ++mt) { accK[nt][mt] = (f32x4)0.f; accV[nt][mt] = (f32x4)0.f; }
        #pragma unroll
        for (int kt = 0; kt < 2; ++kt) {
            bf16x8 a[4];
            #pragma unroll
            for (int mt = 0; mt < 4; ++mt)
                a[mt] = *(const bf16x8*)&sLanes[(mt * 16 + lm) * 80 + kt * 32 + quad * 8];
            #pragma unroll
            for (int nt = 0; nt < 2; ++nt)
                #pragma unroll
                for (int mt = 0; mt < 4; ++mt) {
                    accK[nt][mt] = MFMA(a[mt], wbK[kt][nt], accK[nt][mt]);
                    accV[nt][mt] = MFMA(a[mt], wbV[kt][nt], accV[nt][mt]);
                }
        }
        #pragma unroll
        for (int nt = 0; nt < 2; ++nt) {
            const int f = fbase + nt * 16 + lm;
            #pragma unroll
            for (int mt = 0; mt < 4; ++mt) {
                const int l0 = mt * 16 + quad * 4;
                #pragma unroll
                for (int r = 0; r < 4; ++r) sK[(l0 + r) * 136 + f] = f2bf(accK[nt][mt][r]);
                st4bf(&sVt[f * 72 + l0], accV[nt][mt]);
            }
        }
    }

    // ---------- Phase C: Q projection (wave-local g-slice), pre-scaled ----------
    {
        f32x4 acc[2][2];
        #pragma unroll
        for (int nt = 0; nt < 2; ++nt)
            #pragma unroll
            for (int mt = 0; mt < 2; ++mt) acc[nt][mt] = (f32x4)0.f;
        #pragma unroll
        for (int kt = 0; kt < 4; ++kt) {
            bf16x8 a[2];
            #pragma unroll
            for (int mt = 0; mt < 2; ++mt)
                a[mt] = *(const bf16x8*)&sVehB[(mt * 16 + lm) * 136 + kt * 32 + quad * 8];
            #pragma unroll
            for (int nt = 0; nt < 2; ++nt)
                #pragma unroll
                for (int mt = 0; mt < 2; ++mt) acc[nt][mt] = MFMA(a[mt], wq[kt][nt], acc[nt][mt]);
        }
        const float sc = 0.17677669529663687f;   // 1/sqrt(32)
        #pragma unroll
        for (int nt = 0; nt < 2; ++nt) {
            const int g = fbase + nt * 16 + lm;
            #pragma unroll
            for (int mt = 0; mt < 2; ++mt) {
                const int t0 = mt * 16 + quad * 4;
                #pragma unroll
                for (int r = 0; r < 4; ++r) sQ[(t0 + r) * 136 + g] = f2bf(acc[nt][mt][r] * sc);
            }
        }
    }

    // preload E fragments now (consumed after barrier 3; latency hidden)
    bf16x8 wc[4][2];
    #pragma unroll
    for (int kt = 0; kt < 4; ++kt)
        #pragma unroll
        for (int nt = 0; nt < 2; ++nt)
            wc[kt][nt] = ldWfrag(Wc, (fbase + nt * 16 + lm) * 128 + kt * 32 + quad * 8, isBf16);

    __syncthreads();   // barrier 2: sLanes/sVehB dead; sS overlay may be written

    // ---------- Scores: S^T[l][t] (wave = head) ----------
    {
        bf16x8 a[4], b[2];
        #pragma unroll
        for (int mt = 0; mt < 4; ++mt)
            a[mt] = *(const bf16x8*)&sK[(mt * 16 + lm) * 136 + fbase + quad * 8];
        #pragma unroll
        for (int nt = 0; nt < 2; ++nt)
            b[nt] = *(const bf16x8*)&sQ[(nt * 16 + lm) * 136 + fbase + quad * 8];
        #pragma unroll
        for (int mt = 0; mt < 4; ++mt)
            #pragma unroll
            for (int nt = 0; nt < 2; ++nt) {
                f32x4 acc = MFMA(a[mt], b[nt], (f32x4)0.f);
                const int t = nt * 16 + lm;
                st4bf(&sS[(w * 32 + t) * 72 + mt * 16 + quad * 4], acc);
            }
    }

    // ---------- exp (no max-sub; mask -> 0). Row sums come free in PV. ----------
    {
        #pragma unroll
        for (int t = 0; t < T_; ++t) {
            const int idx = (w * 32 + t) * 72 + lane;
            const float p = ok ? __expf(bf1(sS[idx])) : 0.f;
            sS[idx] = f2bf(p);
        }
        sS[(w * 32 + 30) * 72 + lane] = 0;
        sS[(w * 32 + 31) * 72 + lane] = 0;
    }

    // ---------- PV + ones-MFMA row sums; normalize in epilogue ----------
    {
        bf16x8 bones;
        #pragma unroll
        for (int j = 0; j < 8; ++j) bones[j] = (short)0x3F80;   // 1.0bf
        f32x4 acc[2][2], ssum[2];
        #pragma unroll
        for (int mt = 0; mt < 2; ++mt) {
            ssum[mt] = (f32x4)0.f;
            #pragma unroll
            for (int nt = 0; nt < 2; ++nt) acc[mt][nt] = (f32x4)0.f;
        }
        #pragma unroll
        for (int kt = 0; kt < 2; ++kt) {
            bf16x8 a[2], b[2];
            #pragma unroll
            for (int mt = 0; mt < 2; ++mt)
                a[mt] = *(const bf16x8*)&sS[(w * 32 + mt * 16 + lm) * 72 + kt * 32 + quad * 8];
            #pragma unroll
            for (int nt = 0; nt < 2; ++nt)
                b[nt] = *(const bf16x8*)&sVt[(fbase + nt * 16 + lm) * 72 + kt * 32 + quad * 8];
            #pragma unroll
            for (int mt = 0; mt < 2; ++mt) {
                ssum[mt] = MFMA(a[mt], bones, ssum[mt]);
                #pragma unroll
                for (int nt = 0; nt < 2; ++nt) acc[mt][nt] = MFMA(a[mt], b[nt], acc[mt][nt]);
            }
        }
        #pragma unroll
        for (int mt = 0; mt < 2; ++mt)
            #pragma unroll
            for (int r = 0; r < 4; ++r) {
                const float s = ssum[mt][r];
                const float inv = (s > 0.f) ? 1.f / s : 0.f;   // pad rows -> exact 0
                const int t = mt * 16 + quad * 4 + r;
                #pragma unroll
                for (int nt = 0; nt < 2; ++nt)
                    sO[t * 136 + fbase + nt * 16 + lm] = f2bf(acc[mt][nt][r] * inv);
            }
    }

    // ---------- residual preload (exact fp32 path; issued before barrier 3) ----------
    float res[2][2][4];
    #pragma unroll
    for (int nt = 0; nt < 2; ++nt) {
        const int g = fbase + nt * 16 + lm;
        #pragma unroll
        for (int mt = 0; mt < 2; ++mt)
            #pragma unroll
            for (int r = 0; r < 4; ++r) {
                const int t = mt * 16 + quad * 4 + r;
                float v = 0.f;
                if (t < T_) {
                    const size_t off = ((size_t)t * (B_ * V_) + bv) * F_ + g;
                    v = isBf16 ? bf1(((const unsigned short*)veh)[off])
                               : ((const float*)veh)[off];
                }
                res[nt][mt][r] = v;
            }
    }
    __syncthreads();   // barrier 3: sO complete across waves

    // ---------- Phase E: out = O @ Wc^T + veh ----------
    {
        f32x4 acc[2][2];
        #pragma unroll
        for (int nt = 0; nt < 2; ++nt)
            #pragma unroll
            for (int mt = 0; mt < 2; ++mt) acc[nt][mt] = (f32x4)0.f;
        #pragma unroll
        for (int kt = 0; kt < 4; ++kt) {
            bf16x8 a[2];
            #pragma unroll
            for (int mt = 0; mt < 2; ++mt)
                a[mt] = *(const bf16x8*)&sO[(mt * 16 + lm) * 136 + kt * 32 + quad * 8];
            #pragma unroll
            for (int nt = 0; nt < 2; ++nt)
                #pragma unroll
                for (int mt = 0; mt < 2; ++mt) acc[nt][mt] = MFMA(a[mt], wc[kt][nt], acc[nt][mt]);
        }
        #pragma unroll
        for (int nt = 0; nt < 2; ++nt) {
            const int g = fbase + nt * 16 + lm;
            #pragma unroll
            for (int mt = 0; mt < 2; ++mt)
                #pragma unroll
                for (int r = 0; r < 4; ++r) {
                    const int t = mt * 16 + quad * 4 + r;
                    if (t < T_) {
                        const size_t off = ((size_t)t * (B_ * V_) + bv) * F_ + g;
                        outp[off] = acc[nt][mt][r] + res[nt][mt][r];
                    }
                }
        }
    }
}

extern "C" void kernel_launch(void* const* d_in, const int* in_sizes, int n_in,
                              void* d_out, int out_size, void* d_ws, size_t ws_size,
                              hipStream_t stream) {
    (void)in_sizes; (void)n_in; (void)out_size; (void)d_ws; (void)ws_size;
    lane_attn_kernel<<<dim3(B_ * V_), dim3(256), 0, stream>>>(
        d_in[0], d_in[1], d_in[2], d_in[3], d_in[4], d_in[5], d_in[6],
        (float*)d_out);
}